// Round 1
// 396.735 us; speedup vs baseline: 2.5758x; 2.5758x over previous
//
#include <hip/hip_runtime.h>
#include <math.h>

// MoEGate: scores = sigmoid(x @ W^T); group top-2-sum -> top-4 groups -> top-8
// experts -> normalized weights * 2.5.
//
// R6: the fp32 vector GEMM was structurally capped (no fp32 MFMA on CDNA4;
// 157 TF vector ceiling -> >=191us floor, measured 810us, MfmaUtil=0).
// Replace with f16x3 split-precision MFMA GEMM (v_mfma_f32_16x16x32_f16):
//   x ~= (xh + xl) / 2^6,  w ~= (wh + wl) / 2^10   (RNE f16 splits)
//   65536*dot = xh.wh + xl.wh + xh.wl   (xl.wl dropped: 2^-22 rel/term)
// Power-of-2 scales keep all significant hi/lo parts f16-NORMAL, so the
// result is exact regardless of MFMA denormal-flush behavior. Residual
// score error ~1e-5 == fp32 reorder noise of the previous passing kernel.
//
// Structure: BM=64 x BN=256(full E) x KSPLIT=2 -> 256 blocks = 1/CU,
// 8 waves (2M x 4N). x converted in-kernel to hi/lo f16 LDS tiles
// (XOR-swizzled 128B rows, conflict-free ds_read_b128). W pre-converted to
// k-slice-major f16 hi/lo (L2/L3-resident stream, direct 16B B-frag loads).
// Raw lgkmcnt(0)+s_barrier (not __syncthreads) keeps global prefetch in
// flight across the barrier.

constexpr int T_TOK = 8192;
constexpr int HID   = 7168;
constexpr int NEXP  = 256;

constexpr int BM   = 64;          // token tile
constexpr int BK   = 64;          // k step
constexpr int KSPL = 2;           // k-split (2 -> 256 blocks, 1/CU)
constexpr int KH   = HID / KSPL;  // 3584
constexpr int NIT  = KH / BK;     // 56

typedef __attribute__((ext_vector_type(8))) _Float16 hf8;
typedef __attribute__((ext_vector_type(4))) _Float16 hf4;
typedef __attribute__((ext_vector_type(4))) float    f32x4;

struct hl16 { _Float16 h, l; };
__device__ __forceinline__ hl16 cvt_split(float v, float scale) {
  const float s = v * scale;
  const _Float16 h = (_Float16)s;
  const _Float16 l = (_Float16)(s - (float)h);
  return {h, l};
}

// ---- W pre-convert: fp32 [E][H] -> f16 hi/lo in k-slice-major layout:
// (e, k) -> (k>>3)*(NEXP*8) + e*8 + (k&7). B-fragment = 16B contiguous.
__global__ __launch_bounds__(256)
void convert_w(const float* __restrict__ w, _Float16* __restrict__ wh,
               _Float16* __restrict__ wl) {
  const int gid = blockIdx.x * 256 + threadIdx.x;   // [0, 458752)
  const int e = gid / (HID / 4);
  const int c = gid - e * (HID / 4);
  const float4 v = *(const float4*)(w + (size_t)gid * 4);  // row-major contig
  const int k = 4 * c;
  const size_t o = (size_t)(k >> 3) * (NEXP * 8) + (size_t)e * 8 + (k & 7);
  hf4 h, l;
  hl16 t;
  t = cvt_split(v.x, 1024.f); h.x = t.h; l.x = t.l;
  t = cvt_split(v.y, 1024.f); h.y = t.h; l.y = t.l;
  t = cvt_split(v.z, 1024.f); h.z = t.h; l.z = t.l;
  t = cvt_split(v.w, 1024.f); h.w = t.h; l.w = t.l;
  *(hf4*)(wh + o) = h;
  *(hf4*)(wl + o) = l;
}

// ---- f16x3 MFMA GEMM: part[kp][t][e] = 65536 * partial-dot
__global__ __launch_bounds__(512, 2)
void gemm_mfma(const float* __restrict__ x, const _Float16* __restrict__ wh,
               const _Float16* __restrict__ wl, float* __restrict__ part) {
  __shared__ __attribute__((aligned(16))) _Float16 Ah[2][BM * BK];
  __shared__ __attribute__((aligned(16))) _Float16 Al[2][BM * BK];

  const int tid = threadIdx.x;
  const int l   = tid & 63;
  const int wv  = tid >> 6;           // 8 waves: 2(M) x 4(N)
  const int wm  = wv >> 2;
  const int wn  = wv & 3;
  const int kp  = blockIdx.x;
  const int t0  = blockIdx.y * BM;
  const int kb  = kp * KH;

  // staging: thread -> (row sr, float4-col sc) and (sr, sc+8)
  const int sr = tid >> 3;            // 0..63
  const int sc = tid & 7;             // 0..7
  const float* xrow = x + (size_t)(t0 + sr) * HID + kb + 4 * sc;

  // A-fragment read addressing (bytes), XOR-swizzled
  const int swz   = (l & 7) << 4;
  const int rbyte = (wm * 32 + (l & 15)) * (BK * 2);
  const int kb16  = (l >> 4) * 16;

  // B-fragment base (k-slice-major): lane reads 8 contig f16 of expert row
  const _Float16* bhb = wh + ((size_t)(kb >> 3) + (l >> 4)) * (NEXP * 8)
                           + (size_t)(wn * 64 + (l & 15)) * 8;
  const _Float16* blb = wl + ((size_t)(kb >> 3) + (l >> 4)) * (NEXP * 8)
                           + (size_t)(wn * 64 + (l & 15)) * 8;

  f32x4 acc[2][4] = {};

  float4 xv0 = *(const float4*)(xrow);
  float4 xv1 = *(const float4*)(xrow + 32);

#pragma unroll 2
  for (int it = 0; it < NIT; ++it) {
    // B fragments for this K-step: 16 x 16B (W stream is L1/L2/L3-resident)
    hf8 bh[2][4], bl[2][4];
    const _Float16* bhi = bhb + (size_t)it * (8 * NEXP * 8);
    const _Float16* bli = blb + (size_t)it * (8 * NEXP * 8);
#pragma unroll
    for (int s = 0; s < 2; ++s)
#pragma unroll
      for (int nf = 0; nf < 4; ++nf) {
        bh[s][nf] = *(const hf8*)(bhi + s * (4 * NEXP * 8) + nf * 128);
        bl[s][nf] = *(const hf8*)(bli + s * (4 * NEXP * 8) + nf * 128);
      }

    // convert current x regs -> hi/lo LDS tile (XOR-swizzled rows)
    _Float16* ah = &Ah[it & 1][0];
    _Float16* al = &Al[it & 1][0];
    {
      hf4 h0, h1, g0, g1;
      hl16 t;
      t = cvt_split(xv0.x, 64.f); h0.x = t.h; g0.x = t.l;
      t = cvt_split(xv0.y, 64.f); h0.y = t.h; g0.y = t.l;
      t = cvt_split(xv0.z, 64.f); h0.z = t.h; g0.z = t.l;
      t = cvt_split(xv0.w, 64.f); h0.w = t.h; g0.w = t.l;
      t = cvt_split(xv1.x, 64.f); h1.x = t.h; g1.x = t.l;
      t = cvt_split(xv1.y, 64.f); h1.y = t.h; g1.y = t.l;
      t = cvt_split(xv1.z, 64.f); h1.z = t.h; g1.z = t.l;
      t = cvt_split(xv1.w, 64.f); h1.w = t.h; g1.w = t.l;
      const int wb = sr * (BK * 2);
      const int wsw = (sr & 7) << 4;
      *(hf4*)((char*)ah + wb + ((sc * 8)      ^ wsw)) = h0;
      *(hf4*)((char*)ah + wb + ((sc * 8 + 64) ^ wsw)) = h1;
      *(hf4*)((char*)al + wb + ((sc * 8)      ^ wsw)) = g0;
      *(hf4*)((char*)al + wb + ((sc * 8 + 64) ^ wsw)) = g1;
    }

    // prefetch next x tile (1 iter deep covers ~900cy HBM latency)
    if (it + 1 < NIT) {
      xv0 = *(const float4*)(xrow + (it + 1) * BK);
      xv1 = *(const float4*)(xrow + (it + 1) * BK + 32);
    }

    // lgkmcnt(0): ds_writes visible; raw s_barrier so vmcnt (B/x prefetch)
    // stays in flight across the barrier (unlike __syncthreads's vmcnt(0))
    asm volatile("s_waitcnt lgkmcnt(0)\n\ts_barrier" ::: "memory");

#pragma unroll
    for (int s = 0; s < 2; ++s) {
      hf8 af[2], afl[2];
#pragma unroll
      for (int mf = 0; mf < 2; ++mf) {
        const int off = rbyte + mf * (16 * BK * 2) + ((kb16 + s * 64) ^ swz);
        af[mf]  = *(const hf8*)((const char*)ah + off);
        afl[mf] = *(const hf8*)((const char*)al + off);
      }
#pragma unroll
      for (int mf = 0; mf < 2; ++mf)
#pragma unroll
        for (int nf = 0; nf < 4; ++nf) {
          acc[mf][nf] = __builtin_amdgcn_mfma_f32_16x16x32_f16(
              af[mf],  bh[s][nf], acc[mf][nf], 0, 0, 0);
          acc[mf][nf] = __builtin_amdgcn_mfma_f32_16x16x32_f16(
              afl[mf], bh[s][nf], acc[mf][nf], 0, 0, 0);
          acc[mf][nf] = __builtin_amdgcn_mfma_f32_16x16x32_f16(
              af[mf],  bl[s][nf], acc[mf][nf], 0, 0, 0);
        }
    }
  }

  // epilogue: C/D layout col=lane&15 (expert), row=(lane>>4)*4+reg (token)
  float* pout = part + (size_t)kp * ((size_t)T_TOK * NEXP);
  const int eb = wn * 64 + (l & 15);
  const int tb = t0 + wm * 32 + ((l >> 4) << 2);
#pragma unroll
  for (int mf = 0; mf < 2; ++mf)
#pragma unroll
    for (int j = 0; j < 4; ++j) {
      float* pr = pout + (size_t)(tb + mf * 16 + j) * NEXP + eb;
#pragma unroll
      for (int nf = 0; nf < 4; ++nf) pr[nf * 16] = acc[mf][nf][j];
    }
}

// ---- one wave per token; lane l owns experts 4l..4l+3 in registers
__global__ __launch_bounds__(256)
void routing_kernel(const float* __restrict__ part,
                    const float* __restrict__ bias,
                    float* __restrict__ out) {
  const int lane = threadIdx.x & 63;
  const int t = blockIdx.x * 4 + (threadIdx.x >> 6);
  const int e_base = 4 * lane;

  // reduce K-split partials, unscale (x*64 * w*1024 = 2^16), sigmoid, +bias
  float4 z = make_float4(0.f, 0.f, 0.f, 0.f);
#pragma unroll
  for (int kp = 0; kp < KSPL; ++kp) {
    float4 v = *(const float4*)(part + (size_t)kp * T_TOK * NEXP +
                                (size_t)t * NEXP + e_base);
    z.x += v.x; z.y += v.y; z.z += v.z; z.w += v.w;
  }
  constexpr float INV = 1.f / 65536.f;
  float s[4], sb[4];
  const float4 b4 = *(const float4*)(bias + e_base);
  s[0] = 1.f / (1.f + expf(-z.x * INV)); sb[0] = s[0] + b4.x;
  s[1] = 1.f / (1.f + expf(-z.y * INV)); sb[1] = s[1] + b4.y;
  s[2] = 1.f / (1.f + expf(-z.z * INV)); sb[2] = s[2] + b4.z;
  s[3] = 1.f / (1.f + expf(-z.w * INV)); sb[3] = s[3] + b4.w;

  // lane-local top-2 of 4 (pairwise tournament)
  const float Ma = fmaxf(sb[0], sb[1]), ma = fminf(sb[0], sb[1]);
  const float Mb = fmaxf(sb[2], sb[3]), mb = fminf(sb[2], sb[3]);
  float m1 = fmaxf(Ma, Mb);
  float m2 = fmaxf(fminf(Ma, Mb), fmaxf(ma, mb));
  // merge (m1,m2) pairs across the 8 lanes of the group
#pragma unroll
  for (int off = 1; off < 8; off <<= 1) {
    const float o1 = __shfl_xor(m1, off);
    const float o2 = __shfl_xor(m2, off);
    const float n1 = fmaxf(m1, o1);
    m2 = fmaxf(fminf(m1, o1), fmaxf(m2, o2));
    m1 = n1;
  }
  const float gsum = m1 + m2;

  float gs[8];
#pragma unroll
  for (int g = 0; g < 8; ++g) gs[g] = __shfl(gsum, g * 8);

  // stable top-4 groups (strict >, lowest index on ties)
  unsigned gmask = 0;
#pragma unroll
  for (int r = 0; r < 4; ++r) {
    int best = 0; float bv = -3.4e38f;
#pragma unroll
    for (int g = 0; g < 8; ++g) {
      const bool ok = (((gmask >> g) & 1u) == 0) && (gs[g] > bv);
      bv = ok ? gs[g] : bv;
      best = ok ? g : best;
    }
    gmask |= 1u << best;
  }

  const bool sel = (gmask >> (lane >> 3)) & 1u;
#pragma unroll
  for (int j = 0; j < 4; ++j) sb[j] = sel ? sb[j] : -3.4e38f;

  // top-8 experts: 8 rounds of wave-argmax (ties -> lowest expert index)
  float wq[8]; float iq[8];
#pragma unroll
  for (int r = 0; r < 8; ++r) {
    float bv = sb[0]; int bi = e_base; float bs = s[0];
#pragma unroll
    for (int j = 1; j < 4; ++j) {
      const bool c = sb[j] > bv;
      bv = c ? sb[j] : bv; bi = c ? e_base + j : bi; bs = c ? s[j] : bs;
    }
#pragma unroll
    for (int off = 1; off < 64; off <<= 1) {
      const float ov = __shfl_xor(bv, off);
      const int   oi = __shfl_xor(bi, off);
      const float os = __shfl_xor(bs, off);
      const bool take = (ov > bv) || (ov == bv && oi < bi);
      bv = take ? ov : bv; bi = take ? oi : bi; bs = take ? os : bs;
    }
    wq[r] = bs; iq[r] = (float)bi;
#pragma unroll
    for (int j = 0; j < 4; ++j)
      if (e_base + j == bi) sb[j] = -3.4e38f;
  }

  float wsum = 1e-20f;
#pragma unroll
  for (int r = 0; r < 8; ++r) wsum += wq[r];
  const float scale = 2.5f / wsum;

  if (lane == 0) {
    float4* ow = (float4*)(out + (size_t)t * 8);
    ow[0] = make_float4(wq[0] * scale, wq[1] * scale, wq[2] * scale, wq[3] * scale);
    ow[1] = make_float4(wq[4] * scale, wq[5] * scale, wq[6] * scale, wq[7] * scale);
    float4* oi = (float4*)(out + (size_t)T_TOK * 8 + (size_t)t * 8);
    oi[0] = make_float4(iq[0], iq[1], iq[2], iq[3]);
    oi[1] = make_float4(iq[4], iq[5], iq[6], iq[7]);
  }
}

extern "C" void kernel_launch(void* const* d_in, const int* in_sizes, int n_in,
                              void* d_out, int out_size, void* d_ws, size_t ws_size,
                              hipStream_t stream) {
  const float* x    = (const float*)d_in[0];
  const float* w    = (const float*)d_in[1];
  const float* bias = (const float*)d_in[2];
  float* out  = (float*)d_out;
  // ws layout: part [KSPL][T][E] fp32 (16.78 MB), then wh/wl f16 (3.67 MB ea)
  float* part = (float*)d_ws;
  _Float16* wh = (_Float16*)((char*)d_ws + (size_t)KSPL * T_TOK * NEXP * 4);
  _Float16* wl = wh + (size_t)NEXP * HID;

  hipLaunchKernelGGL(convert_w, dim3(NEXP * HID / 4 / 256), dim3(256), 0,
                     stream, w, wh, wl);
  hipLaunchKernelGGL(gemm_mfma, dim3(KSPL, T_TOK / BM), dim3(512), 0, stream,
                     x, wh, wl, part);
  hipLaunchKernelGGL(routing_kernel, dim3(T_TOK / 4), dim3(256), 0, stream,
                     part, bias, out);
}

// Round 2
// 383.884 us; speedup vs baseline: 2.6621x; 1.0335x over previous
//
#include <hip/hip_runtime.h>
#include <math.h>

// MoEGate: scores = sigmoid(x @ W^T); group top-2-sum -> top-4 groups -> top-8
// experts -> normalized weights * 2.5.
//
// R7: R6's f16x3 MFMA GEMM (142us) was latency-bound, not throughput-bound:
// MfmaUtil 26.5% with VALUBusy 12.8% and Occupancy 22% (KSPL=2 -> 1 block/CU
// -> 2 waves/SIMD; nothing to hide B-load L2 latency + barrier skew behind).
// The ~254us of non-gemm time is the constant harness ws-poison (~1.67GB
// writes, was ~210us in R5 too) -- not addressable from kernel source.
// Changes:
//  1. KSPL=4 -> 512 blocks = 2 blocks/CU = 4 waves/SIMD (2x latency pool,
//     desynchronized barriers across the 2 blocks).
//  2. 1Mx8N wave layout (each wave: 32 experts x all 64 tokens): kills the
//     2x duplicated B-fragment L2 reads of the 2Mx4N layout; XCD-clustered
//     block decode puts one kp per XCD (W k-slice 1.84MB < 4MB L2).
//  3. 16x16x32 -> 32x32x16 f16 MFMA: 2382 vs 2075 TF ubench (+15%/FLOP),
//     half the issue slots (24 vs 48 MFMA/iter).
// Numerics unchanged: x ~= (xh+xl)/2^6, w ~= (wh+wl)/2^10 (RNE f16 splits,
// power-of-2 scales keep parts f16-normal); 65536*dot = xh.wh + xl.wh + xh.wl.

constexpr int T_TOK = 8192;
constexpr int HID   = 7168;
constexpr int NEXP  = 256;

constexpr int BM   = 64;          // token tile
constexpr int BK   = 64;          // k step
constexpr int KSPL = 4;           // k-split -> 512 blocks, 2/CU
constexpr int KH   = HID / KSPL;  // 1792
constexpr int NIT  = KH / BK;     // 28

typedef __attribute__((ext_vector_type(8)))  _Float16 hf8;
typedef __attribute__((ext_vector_type(4)))  _Float16 hf4;
typedef __attribute__((ext_vector_type(16))) float    f32x16;

struct hl16 { _Float16 h, l; };
__device__ __forceinline__ hl16 cvt_split(float v, float scale) {
  const float s = v * scale;
  const _Float16 h = (_Float16)s;
  const _Float16 l = (_Float16)(s - (float)h);
  return {h, l};
}

// ---- W pre-convert: fp32 [E][H] -> f16 hi/lo in k-slice-major layout:
// (e, k) -> (k>>3)*(NEXP*8) + e*8 + (k&7). B-fragment = 16B contiguous.
__global__ __launch_bounds__(256)
void convert_w(const float* __restrict__ w, _Float16* __restrict__ wh,
               _Float16* __restrict__ wl) {
  const int gid = blockIdx.x * 256 + threadIdx.x;   // [0, 458752)
  const int e = gid / (HID / 4);
  const int c = gid - e * (HID / 4);
  const float4 v = *(const float4*)(w + (size_t)gid * 4);  // row-major contig
  const int k = 4 * c;
  const size_t o = (size_t)(k >> 3) * (NEXP * 8) + (size_t)e * 8 + (k & 7);
  hf4 h, l;
  hl16 t;
  t = cvt_split(v.x, 1024.f); h.x = t.h; l.x = t.l;
  t = cvt_split(v.y, 1024.f); h.y = t.h; l.y = t.l;
  t = cvt_split(v.z, 1024.f); h.z = t.h; l.z = t.l;
  t = cvt_split(v.w, 1024.f); h.w = t.h; l.w = t.l;
  *(hf4*)(wh + o) = h;
  *(hf4*)(wl + o) = l;
}

// ---- f16x3 MFMA GEMM (32x32x16): part[kp][t][e] = 65536 * partial-dot
__global__ __launch_bounds__(512, 4)
void gemm_mfma(const float* __restrict__ x, const _Float16* __restrict__ wh,
               const _Float16* __restrict__ wl, float* __restrict__ part) {
  __shared__ __attribute__((aligned(16))) _Float16 Ah[2][BM * BK];  // 16 KB
  __shared__ __attribute__((aligned(16))) _Float16 Al[2][BM * BK];  // 16 KB

  const int tid = threadIdx.x;
  const int l   = tid & 63;
  const int wn  = tid >> 6;           // 8 waves: 32 experts each, all 64 rows

  // XCD-clustered decode: round-robin dispatch -> b&7 ~ XCD; give each XCD
  // one kp so its W k-slice (1.84 MB hi+lo) stays L2-resident.
  const int b  = blockIdx.x;          // [0, 512)
  const int kp = (b & 7) >> 1;        // 2 XCDs per kp
  const int tt = (b >> 3) + 64 * (b & 1);
  const int t0 = tt * BM;
  const int kb = kp * KH;

  // staging: thread -> (row sr, float4-col sc), two float4 per row
  const int sr = tid >> 3;            // 0..63
  const int sc = tid & 7;             // 0..7
  const float* xrow = x + (size_t)(t0 + sr) * HID + kb + 4 * sc;

  // A-fragment read addressing (32x32x16: row=l&31, k=(l>>5)*8+j)
  const int swz   = (l & 7) << 4;     // XOR swizzle (st_16x32 style)
  const int lrow  = l & 31;
  const int khalf = l >> 5;           // 0/1

  // B-fragment base (k-slice-major): lane reads 8 contig f16 of expert row
  const _Float16* bhb = wh + ((size_t)(kb >> 3) + khalf) * (NEXP * 8)
                           + (size_t)(wn * 32 + lrow) * 8;
  const _Float16* blb = wl + ((size_t)(kb >> 3) + khalf) * (NEXP * 8)
                           + (size_t)(wn * 32 + lrow) * 8;

  f32x16 acc[2] = {};                 // mt = 0/1: token rows [0,32), [32,64)

  float4 xv0 = *(const float4*)(xrow);
  float4 xv1 = *(const float4*)(xrow + 32);

#pragma unroll 2
  for (int it = 0; it < NIT; ++it) {
    // issue next x tile first (HBM latency hides under this whole iter)
    float4 xn0, xn1;
    const bool more = (it + 1 < NIT);
    if (more) {
      xn0 = *(const float4*)(xrow + (it + 1) * BK);
      xn1 = *(const float4*)(xrow + (it + 1) * BK + 32);
    }

    // B fragments for this K-step: 8 x 16B (L2-resident W stream, deduped)
    hf8 bh[4], bl[4];
    const _Float16* bhi = bhb + (size_t)it * (8 * NEXP * 8);
    const _Float16* bli = blb + (size_t)it * (8 * NEXP * 8);
#pragma unroll
    for (int ks = 0; ks < 4; ++ks) {
      bh[ks] = *(const hf8*)(bhi + ks * (2 * NEXP * 8));
      bl[ks] = *(const hf8*)(bli + ks * (2 * NEXP * 8));
    }

    // convert current x regs -> hi/lo LDS tile (XOR-swizzled 128B rows)
    _Float16* ah = &Ah[it & 1][0];
    _Float16* al = &Al[it & 1][0];
    {
      hf4 h0, h1, g0, g1;
      hl16 t;
      t = cvt_split(xv0.x, 64.f); h0.x = t.h; g0.x = t.l;
      t = cvt_split(xv0.y, 64.f); h0.y = t.h; g0.y = t.l;
      t = cvt_split(xv0.z, 64.f); h0.z = t.h; g0.z = t.l;
      t = cvt_split(xv0.w, 64.f); h0.w = t.h; g0.w = t.l;
      t = cvt_split(xv1.x, 64.f); h1.x = t.h; g1.x = t.l;
      t = cvt_split(xv1.y, 64.f); h1.y = t.h; g1.y = t.l;
      t = cvt_split(xv1.z, 64.f); h1.z = t.h; g1.z = t.l;
      t = cvt_split(xv1.w, 64.f); h1.w = t.h; g1.w = t.l;
      const int wb  = sr * (BK * 2);
      const int wsw = (sr & 7) << 4;
      *(hf4*)((char*)ah + wb + ((sc * 8)      ^ wsw)) = h0;
      *(hf4*)((char*)ah + wb + ((sc * 8 + 64) ^ wsw)) = h1;
      *(hf4*)((char*)al + wb + ((sc * 8)      ^ wsw)) = g0;
      *(hf4*)((char*)al + wb + ((sc * 8 + 64) ^ wsw)) = g1;
    }

    // lgkmcnt(0): ds_writes visible; raw s_barrier so vmcnt (B/x prefetch)
    // stays in flight across the barrier (unlike __syncthreads's vmcnt(0))
    asm volatile("s_waitcnt lgkmcnt(0)\n\ts_barrier" ::: "memory");

#pragma unroll
    for (int ks = 0; ks < 4; ++ks) {
      const int cb = (ks * 32 + khalf * 16) ^ swz;
      const hf8 a0h = *(const hf8*)((const char*)ah + lrow * 128 + cb);
      const hf8 a1h = *(const hf8*)((const char*)ah + (32 + lrow) * 128 + cb);
      const hf8 a0l = *(const hf8*)((const char*)al + lrow * 128 + cb);
      const hf8 a1l = *(const hf8*)((const char*)al + (32 + lrow) * 128 + cb);
      acc[0] = __builtin_amdgcn_mfma_f32_32x32x16_f16(a0h, bh[ks], acc[0], 0, 0, 0);
      acc[1] = __builtin_amdgcn_mfma_f32_32x32x16_f16(a1h, bh[ks], acc[1], 0, 0, 0);
      acc[0] = __builtin_amdgcn_mfma_f32_32x32x16_f16(a0l, bh[ks], acc[0], 0, 0, 0);
      acc[1] = __builtin_amdgcn_mfma_f32_32x32x16_f16(a1l, bh[ks], acc[1], 0, 0, 0);
      acc[0] = __builtin_amdgcn_mfma_f32_32x32x16_f16(a0h, bl[ks], acc[0], 0, 0, 0);
      acc[1] = __builtin_amdgcn_mfma_f32_32x32x16_f16(a1h, bl[ks], acc[1], 0, 0, 0);
    }

    if (more) { xv0 = xn0; xv1 = xn1; }
  }

  // epilogue: 32x32 C/D layout: col=lane&31 (expert),
  // row = (reg&3) + 8*(reg>>2) + 4*(lane>>5) (token)
  float* pout = part + (size_t)kp * ((size_t)T_TOK * NEXP);
  const int e = wn * 32 + lrow;
#pragma unroll
  for (int mt = 0; mt < 2; ++mt)
#pragma unroll
    for (int g = 0; g < 4; ++g) {
      const int r0 = t0 + mt * 32 + 8 * g + 4 * khalf;
#pragma unroll
      for (int j = 0; j < 4; ++j)
        pout[(size_t)(r0 + j) * NEXP + e] = acc[mt][4 * g + j];
    }
}

// ---- one wave per token; lane l owns experts 4l..4l+3 in registers
__global__ __launch_bounds__(256)
void routing_kernel(const float* __restrict__ part,
                    const float* __restrict__ bias,
                    float* __restrict__ out) {
  const int lane = threadIdx.x & 63;
  const int t = blockIdx.x * 4 + (threadIdx.x >> 6);
  const int e_base = 4 * lane;

  // reduce K-split partials, unscale (x*64 * w*1024 = 2^16), sigmoid, +bias
  float4 z = make_float4(0.f, 0.f, 0.f, 0.f);
#pragma unroll
  for (int kp = 0; kp < KSPL; ++kp) {
    float4 v = *(const float4*)(part + (size_t)kp * T_TOK * NEXP +
                                (size_t)t * NEXP + e_base);
    z.x += v.x; z.y += v.y; z.z += v.z; z.w += v.w;
  }
  constexpr float INV = 1.f / 65536.f;
  float s[4], sb[4];
  const float4 b4 = *(const float4*)(bias + e_base);
  s[0] = 1.f / (1.f + expf(-z.x * INV)); sb[0] = s[0] + b4.x;
  s[1] = 1.f / (1.f + expf(-z.y * INV)); sb[1] = s[1] + b4.y;
  s[2] = 1.f / (1.f + expf(-z.z * INV)); sb[2] = s[2] + b4.z;
  s[3] = 1.f / (1.f + expf(-z.w * INV)); sb[3] = s[3] + b4.w;

  // lane-local top-2 of 4 (pairwise tournament)
  const float Ma = fmaxf(sb[0], sb[1]), ma = fminf(sb[0], sb[1]);
  const float Mb = fmaxf(sb[2], sb[3]), mb = fminf(sb[2], sb[3]);
  float m1 = fmaxf(Ma, Mb);
  float m2 = fmaxf(fminf(Ma, Mb), fmaxf(ma, mb));
  // merge (m1,m2) pairs across the 8 lanes of the group
#pragma unroll
  for (int off = 1; off < 8; off <<= 1) {
    const float o1 = __shfl_xor(m1, off);
    const float o2 = __shfl_xor(m2, off);
    const float n1 = fmaxf(m1, o1);
    m2 = fmaxf(fminf(m1, o1), fmaxf(m2, o2));
    m1 = n1;
  }
  const float gsum = m1 + m2;

  float gs[8];
#pragma unroll
  for (int g = 0; g < 8; ++g) gs[g] = __shfl(gsum, g * 8);

  // stable top-4 groups (strict >, lowest index on ties)
  unsigned gmask = 0;
#pragma unroll
  for (int r = 0; r < 4; ++r) {
    int best = 0; float bv = -3.4e38f;
#pragma unroll
    for (int g = 0; g < 8; ++g) {
      const bool ok = (((gmask >> g) & 1u) == 0) && (gs[g] > bv);
      bv = ok ? gs[g] : bv;
      best = ok ? g : best;
    }
    gmask |= 1u << best;
  }

  const bool sel = (gmask >> (lane >> 3)) & 1u;
#pragma unroll
  for (int j = 0; j < 4; ++j) sb[j] = sel ? sb[j] : -3.4e38f;

  // top-8 experts: 8 rounds of wave-argmax (ties -> lowest expert index)
  float wq[8]; float iq[8];
#pragma unroll
  for (int r = 0; r < 8; ++r) {
    float bv = sb[0]; int bi = e_base; float bs = s[0];
#pragma unroll
    for (int j = 1; j < 4; ++j) {
      const bool c = sb[j] > bv;
      bv = c ? sb[j] : bv; bi = c ? e_base + j : bi; bs = c ? s[j] : bs;
    }
#pragma unroll
    for (int off = 1; off < 64; off <<= 1) {
      const float ov = __shfl_xor(bv, off);
      const int   oi = __shfl_xor(bi, off);
      const float os = __shfl_xor(bs, off);
      const bool take = (ov > bv) || (ov == bv && oi < bi);
      bv = take ? ov : bv; bi = take ? oi : bi; bs = take ? os : bs;
    }
    wq[r] = bs; iq[r] = (float)bi;
#pragma unroll
    for (int j = 0; j < 4; ++j)
      if (e_base + j == bi) sb[j] = -3.4e38f;
  }

  float wsum = 1e-20f;
#pragma unroll
  for (int r = 0; r < 8; ++r) wsum += wq[r];
  const float scale = 2.5f / wsum;

  if (lane == 0) {
    float4* ow = (float4*)(out + (size_t)t * 8);
    ow[0] = make_float4(wq[0] * scale, wq[1] * scale, wq[2] * scale, wq[3] * scale);
    ow[1] = make_float4(wq[4] * scale, wq[5] * scale, wq[6] * scale, wq[7] * scale);
    float4* oi = (float4*)(out + (size_t)T_TOK * 8 + (size_t)t * 8);
    oi[0] = make_float4(iq[0], iq[1], iq[2], iq[3]);
    oi[1] = make_float4(iq[4], iq[5], iq[6], iq[7]);
  }
}

extern "C" void kernel_launch(void* const* d_in, const int* in_sizes, int n_in,
                              void* d_out, int out_size, void* d_ws, size_t ws_size,
                              hipStream_t stream) {
  const float* x    = (const float*)d_in[0];
  const float* w    = (const float*)d_in[1];
  const float* bias = (const float*)d_in[2];
  float* out  = (float*)d_out;
  // ws layout: part [KSPL][T][E] fp32 (33.6 MB), then wh/wl f16 (3.67 MB ea)
  float* part = (float*)d_ws;
  _Float16* wh = (_Float16*)((char*)d_ws + (size_t)KSPL * T_TOK * NEXP * 4);
  _Float16* wl = wh + (size_t)NEXP * HID;

  hipLaunchKernelGGL(convert_w, dim3(NEXP * HID / 4 / 256), dim3(256), 0,
                     stream, w, wh, wl);
  hipLaunchKernelGGL(gemm_mfma, dim3(512), dim3(512), 0, stream,
                     x, wh, wl, part);
  hipLaunchKernelGGL(routing_kernel, dim3(T_TOK / 4), dim3(256), 0, stream,
                     part, bias, out);
}